// Round 6
// baseline (908.481 us; speedup 1.0000x reference)
//
#include <hip/hip_runtime.h>
#include <hip/hip_bf16.h>

typedef short short8 __attribute__((ext_vector_type(8)));
typedef float floatx4 __attribute__((ext_vector_type(4)));

__device__ __forceinline__ short f2bf(float x) {
  __hip_bfloat16 h = __float2bfloat16(x);
  return __builtin_bit_cast(short, h);
}

// Load 8 consecutive elements at element index idx, as bf16 bits.
// f32=1: source is float32 (external inputs). f32=0: source is bf16 (internal).
__device__ __forceinline__ short8 load8(const void* __restrict__ p, size_t idx, int f32) {
  if (f32) {
    const float* f = (const float*)p + idx;
    short8 r;
#pragma unroll
    for (int i = 0; i < 8; i++) r[i] = f2bf(f[i]);
    return r;
  }
  return *(const short8*)((const short*)p + idx);
}

// C[m,n] = sum_k A[m,k] * B[n,k].  A: MxK (element offset aoff), B: NxK.
// omode 0: C bf16 row-major. 1: C bf16 scattered to vT layout
//   C[((m>>11)*1024 + n)*2048 + (m&2047)]. 2: C float32 row-major (d_out).
__global__ __launch_bounds__(256) void gemm_bt(
    const void* __restrict__ A,
    const void* __restrict__ Bm,
    void* __restrict__ C,
    int M, int N, int K, int omode,
    int af32, int bf32, unsigned long long aoff)
{
  __shared__ short As[64][72];  // 144 B stride: b128-aligned, 2-way bank alias only (free)
  __shared__ short Bs[64][72];
  const int tid  = threadIdx.x;
  const int wave = tid >> 6, lane = tid & 63;
  const int quad = lane >> 4, l15 = lane & 15;
  const int m0 = blockIdx.y * 64, n0 = blockIdx.x * 64;
  const int wr = (wave >> 1) * 32, wc = (wave & 1) * 32;

  floatx4 acc00 = {}, acc01 = {}, acc10 = {}, acc11 = {};

  const int r0 = tid >> 3, kc0 = (tid & 7) << 3;
  const int r1 = r0 + 32;

  for (int k0 = 0; k0 < K; k0 += 64) {
    __syncthreads();
    *(short8*)&As[r0][kc0] = load8(A, aoff + (size_t)(m0 + r0) * K + k0 + kc0, af32);
    *(short8*)&As[r1][kc0] = load8(A, aoff + (size_t)(m0 + r1) * K + k0 + kc0, af32);
    short8 bz = {};
    *(short8*)&Bs[r0][kc0] = (n0 + r0 < N) ? load8(Bm, (size_t)(n0 + r0) * K + k0 + kc0, bf32) : bz;
    *(short8*)&Bs[r1][kc0] = (n0 + r1 < N) ? load8(Bm, (size_t)(n0 + r1) * K + k0 + kc0, bf32) : bz;
    __syncthreads();
#pragma unroll
    for (int kk = 0; kk < 64; kk += 32) {
      short8 a0 = *(const short8*)&As[wr + l15][kk + quad * 8];
      short8 a1 = *(const short8*)&As[wr + 16 + l15][kk + quad * 8];
      short8 b0 = *(const short8*)&Bs[wc + l15][kk + quad * 8];
      short8 b1 = *(const short8*)&Bs[wc + 16 + l15][kk + quad * 8];
      acc00 = __builtin_amdgcn_mfma_f32_16x16x32_bf16(a0, b0, acc00, 0, 0, 0);
      acc01 = __builtin_amdgcn_mfma_f32_16x16x32_bf16(a0, b1, acc01, 0, 0, 0);
      acc10 = __builtin_amdgcn_mfma_f32_16x16x32_bf16(a1, b0, acc10, 0, 0, 0);
      acc11 = __builtin_amdgcn_mfma_f32_16x16x32_bf16(a1, b1, acc11, 0, 0, 0);
    }
  }

  floatx4 accs[2][2] = {{acc00, acc01}, {acc10, acc11}};
#pragma unroll
  for (int i = 0; i < 2; i++)
#pragma unroll
    for (int j = 0; j < 2; j++)
#pragma unroll
      for (int r = 0; r < 4; r++) {
        int row = m0 + wr + i * 16 + quad * 4 + r;   // C/D: row=(lane>>4)*4+reg
        int col = n0 + wc + j * 16 + l15;            //      col=lane&15
        if (col < N) {
          float v = accs[i][j][r];
          if (omode == 2) {
            ((float*)C)[(size_t)row * N + col] = v;            // fp32 final output
          } else if (omode == 1) {
            ((__hip_bfloat16*)C)[(((size_t)(row >> 11) * 1024 + col) << 11) + (row & 2047)] =
                __float2bfloat16(v);
          } else {
            ((__hip_bfloat16*)C)[(size_t)row * N + col] = __float2bfloat16(v);
          }
        }
      }
}

// In-place interleaved RoPE on internal bf16 buffers.
// ppp = pairs per position (256 for q_R, 16 for k_R). pos = (g/ppp) & 2047.
__global__ __launch_bounds__(256) void rope_kernel(__hip_bfloat16* p, int n_pairs, int ppp) {
  int g = blockIdx.x * 256 + threadIdx.x;
  if (g >= n_pairs) return;
  int i = g & 15;
  int pos = (g / ppp) & 2047;
  float inv_freq = powf(10000.0f, -(float)i * (1.0f / 16.0f));
  float ang = (float)pos * inv_freq;
  float sn, cs;
  sincosf(ang, &sn, &cs);
  float x1 = __bfloat162float(p[2 * g]);
  float x2 = __bfloat162float(p[2 * g + 1]);
  p[2 * g]     = __float2bfloat16(x1 * cs - x2 * sn);
  p[2 * g + 1] = __float2bfloat16(x1 * sn + x2 * cs);
}

// Per-batch causal flash attention. All pointers pre-offset to batch b.
// qC:(S,H,64) qR:(S,H,32) kC:(S,H,64) kR:(S,32) vT:(H*64,S) -> O:(S,H*64)  (bf16)
__global__ __launch_bounds__(256) void mla_attn(
    const __hip_bfloat16* __restrict__ qC,
    const __hip_bfloat16* __restrict__ qR,
    const __hip_bfloat16* __restrict__ kC,
    const __hip_bfloat16* __restrict__ kR,
    const __hip_bfloat16* __restrict__ vT,
    __hip_bfloat16* __restrict__ O)
{
  const int tid  = threadIdx.x;
  const int wave = tid >> 6, lane = tid & 63;
  const int quad = lane >> 4, l15 = lane & 15;
  const int h = blockIdx.y;
  const int q0 = blockIdx.x * 64;

  __shared__ short Ks[32][104];      // 32 keys x 96 dims (+8 pad)
  __shared__ short Vt[64][40];       // 64 dv x 32 keys (+8 pad)
  __shared__ short Ps[4][16][40];    // per-wave P round-trip (C->A layout)

  const short* qCs = reinterpret_cast<const short*>(qC);
  const short* qRs = reinterpret_cast<const short*>(qR);
  const short* kCs = reinterpret_cast<const short*>(kC);
  const short* kRs = reinterpret_cast<const short*>(kR);
  const short* Vs  = reinterpret_cast<const short*>(vT);

  // Q fragments (A-operand: m=lane&15, k=quad*8+j), loaded once
  const int qrow = q0 + wave * 16 + l15;
  const size_t qcbase = ((size_t)qrow * 16 + h) * 64;
  const size_t qrbase = ((size_t)qrow * 16 + h) * 32;
  short8 aq0 = *(const short8*)&qCs[qcbase + quad * 8];
  short8 aq1 = *(const short8*)&qCs[qcbase + 32 + quad * 8];
  short8 aq2 = *(const short8*)&qRs[qrbase + quad * 8];

  const float MASKV = -30000.0f;
  float mrow[4], lrow[4];
  floatx4 accO[4] = {};
#pragma unroll
  for (int r = 0; r < 4; r++) { mrow[r] = MASKV; lrow[r] = 0.f; }

  const float scale = 0.10206207261596575f;  // 1/sqrt(96)

  const int nkt = (q0 >> 5) + 2;
  for (int kt = 0; kt < nkt; kt++) {
    const int k0 = kt * 32;
    __syncthreads();
    // stage K: 32 keys x 96 dims = 384 vec8 chunks
    {
      int c = tid, key = c / 12, seg = c - key * 12;
      short8 kv;
      if (seg < 8) kv = *(const short8*)&kCs[((size_t)(k0 + key) * 16 + h) * 64 + seg * 8];
      else         kv = *(const short8*)&kRs[(size_t)(k0 + key) * 32 + (seg - 8) * 8];
      *(short8*)&Ks[key][seg * 8] = kv;
      if (tid < 128) {
        c = tid + 256; key = c / 12; seg = c - key * 12;
        short8 kv2;
        if (seg < 8) kv2 = *(const short8*)&kCs[((size_t)(k0 + key) * 16 + h) * 64 + seg * 8];
        else         kv2 = *(const short8*)&kRs[(size_t)(k0 + key) * 32 + (seg - 8) * 8];
        *(short8*)&Ks[key][seg * 8] = kv2;
      }
    }
    // stage V (pre-transposed): 64 dv x 32 keys
    {
      int dv = tid >> 2, kc = (tid & 3) << 3;
      short8 vv = *(const short8*)&Vs[((size_t)(h * 64 + dv)) * 2048 + k0 + kc];
      *(short8*)&Vt[dv][kc] = vv;
    }
    __syncthreads();

    float st[2][4];
#pragma unroll
    for (int j = 0; j < 2; j++) {
      short8 b0 = *(const short8*)&Ks[j * 16 + l15][quad * 8];
      short8 b1 = *(const short8*)&Ks[j * 16 + l15][32 + quad * 8];
      short8 b2 = *(const short8*)&Ks[j * 16 + l15][64 + quad * 8];
      floatx4 s = {};
      s = __builtin_amdgcn_mfma_f32_16x16x32_bf16(aq0, b0, s, 0, 0, 0);
      s = __builtin_amdgcn_mfma_f32_16x16x32_bf16(aq1, b1, s, 0, 0, 0);
      s = __builtin_amdgcn_mfma_f32_16x16x32_bf16(aq2, b2, s, 0, 0, 0);
      const int kpos = k0 + j * 16 + l15;
#pragma unroll
      for (int r = 0; r < 4; r++) {
        const int qpos = q0 + wave * 16 + quad * 4 + r;
        float t = fminf(fmaxf(s[r], -80.f), 80.f) * scale;  // clip BEFORE scale (ref order)
        st[j][r] = (kpos <= qpos) ? t : MASKV;
      }
    }
    float ps0[4], ps1[4], alpha[4];
#pragma unroll
    for (int r = 0; r < 4; r++) {
      float tm = fmaxf(st[0][r], st[1][r]);
      tm = fmaxf(tm, __shfl_xor(tm, 1));
      tm = fmaxf(tm, __shfl_xor(tm, 2));
      tm = fmaxf(tm, __shfl_xor(tm, 4));
      tm = fmaxf(tm, __shfl_xor(tm, 8));
      float mnew = fmaxf(mrow[r], tm);
      alpha[r] = __expf(mrow[r] - mnew);
      mrow[r] = mnew;
      float p0 = __expf(st[0][r] - mnew);
      float p1 = __expf(st[1][r] - mnew);
      ps0[r] = p0; ps1[r] = p1;
      float rs = p0 + p1;
      rs += __shfl_xor(rs, 1);
      rs += __shfl_xor(rs, 2);
      rs += __shfl_xor(rs, 4);
      rs += __shfl_xor(rs, 8);
      lrow[r] = lrow[r] * alpha[r] + rs;
    }
#pragma unroll
    for (int c = 0; c < 4; c++)
#pragma unroll
      for (int r = 0; r < 4; r++) accO[c][r] *= alpha[r];

    // P: C-layout -> LDS -> A-operand layout (per-wave private; same-wave DS order)
#pragma unroll
    for (int r = 0; r < 4; r++) {
      Ps[wave][quad * 4 + r][l15]      = f2bf(ps0[r]);
      Ps[wave][quad * 4 + r][16 + l15] = f2bf(ps1[r]);
    }
    short8 ap = *(const short8*)&Ps[wave][l15][quad * 8];
#pragma unroll
    for (int c = 0; c < 4; c++) {
      short8 bv = *(const short8*)&Vt[c * 16 + l15][quad * 8];
      accO[c] = __builtin_amdgcn_mfma_f32_16x16x32_bf16(ap, bv, accO[c], 0, 0, 0);
    }
  }

#pragma unroll
  for (int r = 0; r < 4; r++) {
    float inv = (lrow[r] > 0.f) ? 1.f / lrow[r] : 0.f;
    int s = q0 + wave * 16 + quad * 4 + r;
    size_t obase = (size_t)s * 1024 + h * 64;
#pragma unroll
    for (int c = 0; c < 4; c++)
      O[obase + c * 16 + l15] = __float2bfloat16(accO[c][r] * inv);
  }
}

extern "C" void kernel_launch(void* const* d_in, const int* in_sizes, int n_in,
                              void* d_out, int out_size, void* d_ws, size_t ws_size,
                              hipStream_t stream) {
  // Inputs are float32 (reference dtype); internal pipeline is bf16; output is float32.
  const void* x     = d_in[0];
  const void* W_DQ  = d_in[1];
  const void* W_UQ  = d_in[2];
  const void* W_QR  = d_in[3];
  const void* W_DKV = d_in[4];
  const void* W_UK  = d_in[5];
  const void* W_UV  = d_in[6];
  const void* W_KR  = d_in[7];
  const void* W_O   = d_in[8];
  float* out = (float*)d_out;
  __hip_bfloat16* ws = (__hip_bfloat16*)d_ws;

  dim3 blk(256);

  if (ws_size >= (size_t)76021760) {
    // ---------- big path: whole-problem GEMMs ----------
    __hip_bfloat16* cQ   = ws;                 // 8192x512
    __hip_bfloat16* cKV  = ws + 4194304;       // 8192x512
    __hip_bfloat16* attn = ws;                 // 8192x1024 (overlays dead cQ+cKV)
    __hip_bfloat16* qC   = ws + 8388608;       // (B,S,H,64)
    __hip_bfloat16* qR   = ws + 16777216;      // (B,S,H,32)
    __hip_bfloat16* kC   = ws + 20971520;      // (B,S,H,64)
    __hip_bfloat16* vT   = ws + 29360128;      // (B,1024,2048)
    __hip_bfloat16* kR   = ws + 37748736;      // (B,S,32)

    gemm_bt<<<dim3(8, 128), blk, 0, stream>>>(x,   W_DQ,  cQ,  8192, 512, 1024, 0, 1, 1, 0);
    gemm_bt<<<dim3(8, 128), blk, 0, stream>>>(x,   W_DKV, cKV, 8192, 512, 1024, 0, 1, 1, 0);
    gemm_bt<<<dim3(1, 128), blk, 0, stream>>>(x,   W_KR,  kR,  8192, 32, 1024, 0, 1, 1, 0);
    gemm_bt<<<dim3(16, 128), blk, 0, stream>>>(cQ,  W_UQ,  qC,  8192, 1024, 512, 0, 0, 1, 0);
    gemm_bt<<<dim3(8, 128), blk, 0, stream>>>(cQ,  W_QR,  qR,  8192, 512, 512, 0, 0, 1, 0);
    gemm_bt<<<dim3(16, 128), blk, 0, stream>>>(cKV, W_UK,  kC,  8192, 1024, 512, 0, 0, 1, 0);
    gemm_bt<<<dim3(16, 128), blk, 0, stream>>>(cKV, W_UV,  vT,  8192, 1024, 512, 1, 0, 1, 0);
    rope_kernel<<<dim3(8192), blk, 0, stream>>>(qR, 2097152, 256);
    rope_kernel<<<dim3(512), blk, 0, stream>>>(kR, 131072, 16);
    for (int b = 0; b < 4; b++)
      mla_attn<<<dim3(32, 16), blk, 0, stream>>>(qC + (size_t)b * 2097152, qR + (size_t)b * 1048576,
                                                 kC + (size_t)b * 2097152, kR + (size_t)b * 65536,
                                                 vT + (size_t)b * 2097152, attn + (size_t)b * 2097152);
    gemm_bt<<<dim3(16, 128), blk, 0, stream>>>(attn, W_O, out, 8192, 1024, 1024, 2, 0, 1, 0);
  } else {
    // ---------- small path: per-batch arena (14.1 MB ws + d_out slice scratch) ----------
    __hip_bfloat16* qc = ws;                   // 2M el
    __hip_bfloat16* qr = ws + 2097152;         // 1M el
    __hip_bfloat16* kc = ws + 3145728;         // 2M el
    __hip_bfloat16* kr = ws + 5242880;         // 64K el
    __hip_bfloat16* F  = ws + 5308416;         // 2M el: cQ_b / cKV_b / attn_b

    for (int b = 0; b < 4; b++) {
      unsigned long long xoff = (unsigned long long)b * 2048 * 1024;
      float* outb = out + (size_t)b * 2097152;              // fp32 slice b
      __hip_bfloat16* vtb = (__hip_bfloat16*)outb;          // scratch inside the slice (dead before final)

      gemm_bt<<<dim3(8, 32), blk, 0, stream>>>(x, W_DQ,  F,  2048, 512, 1024, 0, 1, 1, xoff);
      gemm_bt<<<dim3(16, 32), blk, 0, stream>>>(F, W_UQ,  qc, 2048, 1024, 512, 0, 0, 1, 0);
      gemm_bt<<<dim3(8, 32), blk, 0, stream>>>(F, W_QR,  qr, 2048, 512, 512, 0, 0, 1, 0);
      gemm_bt<<<dim3(8, 32), blk, 0, stream>>>(x, W_DKV, F,  2048, 512, 1024, 0, 1, 1, xoff);
      gemm_bt<<<dim3(16, 32), blk, 0, stream>>>(F, W_UK,  kc, 2048, 1024, 512, 0, 0, 1, 0);
      gemm_bt<<<dim3(16, 32), blk, 0, stream>>>(F, W_UV,  vtb, 2048, 1024, 512, 1, 0, 1, 0);
      gemm_bt<<<dim3(1, 32), blk, 0, stream>>>(x, W_KR,  kr, 2048, 32, 1024, 0, 1, 1, xoff);
      rope_kernel<<<dim3(2048), blk, 0, stream>>>(qr, 524288, 256);
      rope_kernel<<<dim3(128), blk, 0, stream>>>(kr, 32768, 16);
      mla_attn<<<dim3(32, 16), blk, 0, stream>>>(qc, qr, kc, kr, vtb, F);
      gemm_bt<<<dim3(16, 32), blk, 0, stream>>>(F, W_O, outb, 2048, 1024, 1024, 2, 0, 1, 0);
    }
  }
}